// Round 1
// baseline (178.962 us; speedup 1.0000x reference)
//
#include <hip/hip_runtime.h>
#include <stdint.h>

#define S 2048
#define DHEAD 64
#define CDIM 256
#define NBATCH 8

typedef __attribute__((ext_vector_type(4))) float f32x4;
typedef __attribute__((ext_vector_type(8))) short s16x8;
typedef __attribute__((ext_vector_type(4))) unsigned short u16x4;

static __device__ __forceinline__ unsigned short f2bf(float f) {
    unsigned int u = __builtin_bit_cast(unsigned int, f);
    unsigned int r = (u + 0x7FFFu + ((u >> 16) & 1u)) >> 16;  // RNE
    return (unsigned short)r;
}

// ---------------- kernel 0: a (fp32) -> a16 (bf16) ----------------
__global__ __launch_bounds__(256) void cvt_a_kernel(const float* __restrict__ a,
                                                    unsigned short* __restrict__ a16,
                                                    int n4) {
    int i = blockIdx.x * 256 + threadIdx.x;
    int stride = gridDim.x * 256;
    for (; i < n4; i += stride) {
        f32x4 v = ((const f32x4*)a)[i];
        u16x4 o;
        o.x = f2bf(v.x); o.y = f2bf(v.y); o.z = f2bf(v.z); o.w = f2bf(v.w);
        ((u16x4*)a16)[i] = o;
    }
}

// ---------------- kernel 1: E = exp(b @ c^T) (bf16), L = row sums (fp32) ----
// block: 256 threads; tile 64 n-rows x 128 m-cols per iter; fp32 math.
// thread micro-tile: 8 n (stride 8) x 4 m (stride 32).
__global__ __launch_bounds__(256) void scores_kernel(
    const float* __restrict__ Bq, const float* __restrict__ Ck,
    unsigned short* __restrict__ E, float* __restrict__ L,
    int b0)
{
    const int lb = blockIdx.y;
    const int gb = b0 + lb;
    const int n0 = blockIdx.x * 64;
    const float* __restrict__ bp = Bq + (size_t)gb * S * DHEAD;
    const float* __restrict__ cp = Ck + (size_t)gb * S * DHEAD;
    unsigned short* __restrict__ Ep = E + (size_t)lb * S * S;

    extern __shared__ char smem[];
    float* bT = (float*)smem;                                   // [64][68] fp32
    float* cT = (float*)(smem + 64*68*4);                       // [128][68] fp32
    unsigned short* Eb = (unsigned short*)(smem + 64*68*4);     // [64][136] bf16, ALIASES cT
    float* sums = (float*)(smem + 64*68*4 + 128*68*4);          // [4][64]

    const int tid = threadIdx.x;
    const int tn = tid & 7;    // n-group (8)
    const int tm = tid >> 3;   // m-group (32)
    const int wv = tid >> 6;
    const int ln = tid & 63;

    // stage b rows n0..n0+63 (row-major [n][k], pad 68)
    for (int idx = tid; idx < 64 * DHEAD; idx += 256) {
        int n = idx >> 6, k = idx & 63;
        bT[n * 68 + k] = bp[(size_t)(n0 + n) * DHEAD + k];
    }

    float Lrun = 0.f;
    for (int mt = 0; mt < S / 128; ++mt) {
        const int m0 = mt * 128;
        __syncthreads();  // prior flush done; bT visible (first iter)
        for (int idx = tid; idx < 128 * DHEAD; idx += 256) {
            int m = idx >> 6, k = idx & 63;
            cT[m * 68 + k] = cp[(size_t)(m0 + m) * DHEAD + k];
        }
        __syncthreads();

        float acc[8][4];
        #pragma unroll
        for (int r = 0; r < 8; ++r)
            #pragma unroll
            for (int j = 0; j < 4; ++j) acc[r][j] = 0.f;

        #pragma unroll 4
        for (int kc = 0; kc < 16; ++kc) {
            f32x4 bv[8], cv[4];
            #pragma unroll
            for (int r = 0; r < 8; ++r)
                bv[r] = *(const f32x4*)&bT[(tn + 8 * r) * 68 + kc * 4];
            #pragma unroll
            for (int j = 0; j < 4; ++j)
                cv[j] = *(const f32x4*)&cT[(tm + 32 * j) * 68 + kc * 4];
            #pragma unroll
            for (int r = 0; r < 8; ++r)
                #pragma unroll
                for (int j = 0; j < 4; ++j)
                    #pragma unroll
                    for (int e = 0; e < 4; ++e)
                        acc[r][j] = __builtin_fmaf(bv[r][e], cv[j][e], acc[r][j]);
        }
        __syncthreads();  // all reads of cT done; Eb may overwrite

        float ps[8];
        #pragma unroll
        for (int r = 0; r < 8; ++r) {
            ps[r] = 0.f;
            #pragma unroll
            for (int j = 0; j < 4; ++j) {
                float e = __expf(acc[r][j]);
                ps[r] += e;
                Eb[(tn + 8 * r) * 136 + tm + 32 * j] = f2bf(e);
            }
        }
        // reduce over tm within wave (lanes sharing tn: stride-8)
        #pragma unroll
        for (int r = 0; r < 8; ++r) {
            ps[r] += __shfl_xor(ps[r], 8);
            ps[r] += __shfl_xor(ps[r], 16);
            ps[r] += __shfl_xor(ps[r], 32);
        }
        if ((ln >> 3) == 0) {
            #pragma unroll
            for (int r = 0; r < 8; ++r) sums[wv * 64 + tn + 8 * r] = ps[r];
        }
        __syncthreads();  // Eb + sums visible
        if (tid < 64)
            Lrun += sums[tid] + sums[64 + tid] + sums[128 + tid] + sums[192 + tid];

        // coalesced flush Eb -> E
        #pragma unroll
        for (int t = 0; t < 4; ++t) {
            int ch = tid + 256 * t;
            int row = ch >> 4, off = ch & 15;
            f32x4 v = *(const f32x4*)&Eb[row * 136 + off * 8];
            *(f32x4*)&Ep[(size_t)(n0 + row) * S + m0 + off * 8] = v;
        }
    }
    if (tid < 64) L[(size_t)lb * S + n0 + tid] = Lrun;
}

// ---------------- kernel 2: out = (a16 @ E^T) / L + a ----------------
// 128x128 tile, BK=32, 4 waves (2x2), 4x4 fragments of 16x16x32 bf16 MFMA.
__global__ __launch_bounds__(256) void gemm_kernel(
    const unsigned short* __restrict__ a16, const unsigned short* __restrict__ E,
    const float* __restrict__ L, const float* __restrict__ afull,
    float* __restrict__ out, int b0)
{
    const int lb = blockIdx.z;
    const int gb = b0 + lb;
    const int n0 = blockIdx.x * 128;
    const int c0 = blockIdx.y * 128;
    const unsigned short* __restrict__ Ap = a16 + (size_t)gb * CDIM * S;
    const unsigned short* __restrict__ Bp = E + (size_t)lb * S * S;
    const float* __restrict__ Lp = L + (size_t)lb * S;
    const float* __restrict__ ap = afull + (size_t)gb * CDIM * S;
    float* __restrict__ op = out + (size_t)gb * CDIM * S;

    __shared__ unsigned short As[128 * 40];  // rows padded to 40 bf16 (80 B) -> conflict-free b128
    __shared__ unsigned short Bs[128 * 40];

    const int tid = threadIdx.x;
    const int lane = tid & 63;
    const int wid = tid >> 6;
    const int wr = wid >> 1, wc = wid & 1;
    const int q = lane >> 4, r15 = lane & 15;

    f32x4 acc[4][4] = {};

    #pragma unroll 2
    for (int kt = 0; kt < S / 32; ++kt) {
        const int k0 = kt * 32;
        __syncthreads();  // protect LDS vs prior reads
        #pragma unroll
        for (int t = 0; t < 2; ++t) {
            int ch = tid + 256 * t;          // 512 chunks of 16 B per matrix
            int row = ch >> 2, off = ch & 3; // 4 chunks per 64-B row
            f32x4 av = *(const f32x4*)&Ap[(size_t)(c0 + row) * S + k0 + off * 8];
            f32x4 bv = *(const f32x4*)&Bp[(size_t)(n0 + row) * S + k0 + off * 8];
            *(f32x4*)&As[row * 40 + off * 8] = av;
            *(f32x4*)&Bs[row * 40 + off * 8] = bv;
        }
        __syncthreads();

        s16x8 af[4], bf[4];
        #pragma unroll
        for (int f = 0; f < 4; ++f) {
            af[f] = *(const s16x8*)&As[(wr * 64 + f * 16 + r15) * 40 + q * 8];
            bf[f] = *(const s16x8*)&Bs[(wc * 64 + f * 16 + r15) * 40 + q * 8];
        }
        #pragma unroll
        for (int i = 0; i < 4; ++i)
            #pragma unroll
            for (int j = 0; j < 4; ++j)
                acc[i][j] = __builtin_amdgcn_mfma_f32_16x16x32_bf16(af[i], bf[j], acc[i][j], 0, 0, 0);
    }

    // epilogue: out = acc / L[n] + a
    float rcpL[4];
    #pragma unroll
    for (int j = 0; j < 4; ++j) {
        int n = n0 + wc * 64 + j * 16 + r15;
        rcpL[j] = 1.0f / Lp[n];
    }
    #pragma unroll
    for (int i = 0; i < 4; ++i) {
        #pragma unroll
        for (int rr = 0; rr < 4; ++rr) {
            int cc = c0 + wr * 64 + i * 16 + q * 4 + rr;
            size_t base = (size_t)cc * S;
            #pragma unroll
            for (int j = 0; j < 4; ++j) {
                int n = n0 + wc * 64 + j * 16 + r15;
                op[base + n] = acc[i][j][rr] * rcpL[j] + ap[base + n];
            }
        }
    }
}

// ---------------- launch ----------------
extern "C" void kernel_launch(void* const* d_in, const int* in_sizes, int n_in,
                              void* d_out, int out_size, void* d_ws, size_t ws_size,
                              hipStream_t stream) {
    const float* a = (const float*)d_in[0];
    const float* b = (const float*)d_in[1];
    const float* c = (const float*)d_in[2];
    float* out = (float*)d_out;

    const size_t a16_bytes = (size_t)NBATCH * CDIM * S * 2;        // 8 MB
    const size_t perb = (size_t)S * S * 2 + (size_t)S * 4;         // ~8.4 MB per batch
    int G = 1;
    if (ws_size > a16_bytes + perb) {
        size_t g = (ws_size - a16_bytes) / perb;
        G = (g >= NBATCH) ? NBATCH : (int)g;
        if (G < 1) G = 1;
    }
    unsigned short* a16 = (unsigned short*)d_ws;
    unsigned short* E = (unsigned short*)((char*)d_ws + a16_bytes);
    float* L = (float*)((char*)d_ws + a16_bytes + (size_t)G * S * S * 2);

    cvt_a_kernel<<<1024, 256, 0, stream>>>(a, a16, NBATCH * CDIM * S / 4);

    const size_t lds1 = 64 * 68 * 4 + 128 * 68 * 4 + 4 * 64 * 4;   // 53248 B
    for (int b0 = 0; b0 < NBATCH; b0 += G) {
        int nb = (NBATCH - b0 < G) ? (NBATCH - b0) : G;
        dim3 g1(S / 64, nb);
        scores_kernel<<<g1, 256, lds1, stream>>>(b, c, E, L, b0);
        dim3 g2(S / 128, CDIM / 128, nb);
        gemm_kernel<<<g2, 256, 0, stream>>>(a16, E, L, a, out, b0);
    }
}

// Round 2
// 79.520 us; speedup vs baseline: 2.2505x; 2.2505x over previous
//
#include <hip/hip_runtime.h>
#include <stdint.h>

#define S 2048
#define DHEAD 64
#define CDIM 256
#define NBATCH 8
#define NMT 16  // S/128 m-tiles

typedef __attribute__((ext_vector_type(4))) float f32x4;
typedef __attribute__((ext_vector_type(8))) short s16x8;
typedef __attribute__((ext_vector_type(8))) _Float16 f16x8;
typedef __attribute__((ext_vector_type(4))) unsigned short u16x4;

static __device__ __forceinline__ unsigned short f2bf(float f) {
    unsigned int u = __builtin_bit_cast(unsigned int, f);
    unsigned int r = (u + 0x7FFFu + ((u >> 16) & 1u)) >> 16;  // RNE
    return (unsigned short)r;
}
static __device__ __forceinline__ unsigned short f2h(float f) {
    _Float16 h = (_Float16)f;
    return __builtin_bit_cast(unsigned short, h);
}

// ---------------- kernel 0: a (fp32) -> a16 (bf16) ----------------
__global__ __launch_bounds__(256) void cvt_a_kernel(const float* __restrict__ a,
                                                    unsigned short* __restrict__ a16,
                                                    int n4) {
    int i = blockIdx.x * 256 + threadIdx.x;
    int stride = gridDim.x * 256;
    for (; i < n4; i += stride) {
        f32x4 v = ((const f32x4*)a)[i];
        u16x4 o;
        o.x = f2bf(v.x); o.y = f2bf(v.y); o.z = f2bf(v.z); o.w = f2bf(v.w);
        ((u16x4*)a16)[i] = o;
    }
}

// ---------------- kernel 1: E = exp(b @ c^T) via f16 MFMA ----------------
// grid (m-tile, n-tile, batch); block 256 = 4 waves (2 wr on m  x 2 wc on n).
// D[m][n] tile 128x128, K=64. Writes E[n][m] bf16 + per-m-tile row sums Lpart.
__global__ __launch_bounds__(256) void scores_kernel(
    const float* __restrict__ Bq, const float* __restrict__ Ck,
    unsigned short* __restrict__ E, float* __restrict__ Lp, int b0)
{
    const int lb = blockIdx.z;
    const int gb = b0 + lb;
    const int mt = blockIdx.x;
    const int m0 = mt * 128;
    const int n0 = blockIdx.y * 128;
    const float* __restrict__ bp = Bq + (size_t)gb * S * DHEAD;
    const float* __restrict__ cp = Ck + (size_t)gb * S * DHEAD;
    unsigned short* __restrict__ Ep = E + (size_t)lb * S * S;

    extern __shared__ char smem[];
    unsigned short* cs = (unsigned short*)smem;        // [128][72] f16 (m rows)
    unsigned short* bs = cs + 128 * 72;                // [128][72] f16 (n rows)
    unsigned short* es = (unsigned short*)smem;        // [128][136] bf16, ALIASES cs/bs
    float* Lsh = (float*)(smem + 2 * 128 * 72 * 2);    // [2][128]

    const int tid = threadIdx.x;
    const int lane = tid & 63;
    const int wid = tid >> 6;
    const int wr = wid >> 1, wc = wid & 1;
    const int q = lane >> 4, r15 = lane & 15;

    // stage c (m rows) and b (n rows) tiles, fp32 -> f16
    #pragma unroll
    for (int t = 0; t < 8; ++t) {
        int ch = tid + 256 * t;            // 2048 chunks of 4 floats per matrix
        int row = ch >> 4, c4 = ch & 15;   // 16 chunks per 64-float row
        f32x4 cv = *(const f32x4*)&cp[(size_t)(m0 + row) * DHEAD + c4 * 4];
        f32x4 bv = *(const f32x4*)&bp[(size_t)(n0 + row) * DHEAD + c4 * 4];
        u16x4 co, bo;
        co.x = f2h(cv.x); co.y = f2h(cv.y); co.z = f2h(cv.z); co.w = f2h(cv.w);
        bo.x = f2h(bv.x); bo.y = f2h(bv.y); bo.z = f2h(bv.z); bo.w = f2h(bv.w);
        *(u16x4*)&cs[row * 72 + c4 * 4] = co;
        *(u16x4*)&bs[row * 72 + c4 * 4] = bo;
    }
    __syncthreads();

    f32x4 acc[4][4] = {};
    #pragma unroll
    for (int kk = 0; kk < 2; ++kk) {
        f16x8 af[4], bf[4];
        #pragma unroll
        for (int i = 0; i < 4; ++i)
            af[i] = *(const f16x8*)&cs[(wr * 64 + i * 16 + r15) * 72 + kk * 32 + q * 8];
        #pragma unroll
        for (int j = 0; j < 4; ++j)
            bf[j] = *(const f16x8*)&bs[(wc * 64 + j * 16 + r15) * 72 + kk * 32 + q * 8];
        #pragma unroll
        for (int i = 0; i < 4; ++i)
            #pragma unroll
            for (int j = 0; j < 4; ++j)
                acc[i][j] = __builtin_amdgcn_mfma_f32_16x16x32_f16(af[i], bf[j], acc[i][j], 0, 0, 0);
    }

    // exp + pack + per-lane partial row sums (sum over m for fixed n)
    u16x4 pk[4][4];
    float sj[4] = {0.f, 0.f, 0.f, 0.f};
    #pragma unroll
    for (int i = 0; i < 4; ++i) {
        #pragma unroll
        for (int j = 0; j < 4; ++j) {
            float e0 = __expf(acc[i][j][0]);
            float e1 = __expf(acc[i][j][1]);
            float e2 = __expf(acc[i][j][2]);
            float e3 = __expf(acc[i][j][3]);
            pk[i][j].x = f2bf(e0); pk[i][j].y = f2bf(e1);
            pk[i][j].z = f2bf(e2); pk[i][j].w = f2bf(e3);
            sj[j] += (e0 + e1) + (e2 + e3);
        }
    }
    // reduce over q groups (m direction) within wave
    #pragma unroll
    for (int j = 0; j < 4; ++j) {
        sj[j] += __shfl_xor(sj[j], 16);
        sj[j] += __shfl_xor(sj[j], 32);
    }

    __syncthreads();  // all fragment ds_reads done -> es may overwrite cs/bs

    #pragma unroll
    for (int i = 0; i < 4; ++i)
        #pragma unroll
        for (int j = 0; j < 4; ++j) {
            int nl = wc * 64 + j * 16 + r15;
            int ml = wr * 64 + i * 16 + q * 4;
            *(u16x4*)&es[nl * 136 + ml] = pk[i][j];
        }
    if (q == 0) {
        #pragma unroll
        for (int j = 0; j < 4; ++j)
            Lsh[wr * 128 + wc * 64 + j * 16 + r15] = sj[j];
    }
    __syncthreads();

    if (tid < 128)
        Lp[(size_t)lb * NMT * S + (size_t)mt * S + n0 + tid] = Lsh[tid] + Lsh[128 + tid];

    // coalesced flush es -> E[n][m]
    #pragma unroll
    for (int t = 0; t < 8; ++t) {
        int ch = tid + 256 * t;            // 2048 chunks of 8 bf16
        int row = ch >> 4, off = ch & 15;
        f32x4 v = *(const f32x4*)&es[row * 136 + off * 8];
        *(f32x4*)&Ep[(size_t)(n0 + row) * S + m0 + off * 8] = v;
    }
}

// ---------------- kernel 2: out = (a16 @ E^T) / L + a ----------------
// 128x128 tile, BK=32, 4 waves (2x2), 4x4 fragments of 16x16x32 bf16 MFMA.
__global__ __launch_bounds__(256) void gemm_kernel(
    const unsigned short* __restrict__ a16, const unsigned short* __restrict__ E,
    const float* __restrict__ Lp, const float* __restrict__ afull,
    float* __restrict__ out, int b0)
{
    const int lb = blockIdx.z;
    const int gb = b0 + lb;
    const int n0 = blockIdx.x * 128;
    const int c0 = blockIdx.y * 128;
    const unsigned short* __restrict__ Ap = a16 + (size_t)gb * CDIM * S;
    const unsigned short* __restrict__ Bp = E + (size_t)lb * S * S;
    const float* __restrict__ ap = afull + (size_t)gb * CDIM * S;
    float* __restrict__ op = out + (size_t)gb * CDIM * S;

    __shared__ unsigned short As[128 * 40];  // rows padded to 40 bf16 (80 B)
    __shared__ unsigned short Bs[128 * 40];

    const int tid = threadIdx.x;
    const int lane = tid & 63;
    const int wid = tid >> 6;
    const int wr = wid >> 1, wc = wid & 1;
    const int q = lane >> 4, r15 = lane & 15;

    f32x4 acc[4][4] = {};

    #pragma unroll 2
    for (int kt = 0; kt < S / 32; ++kt) {
        const int k0 = kt * 32;
        __syncthreads();
        #pragma unroll
        for (int t = 0; t < 2; ++t) {
            int ch = tid + 256 * t;
            int row = ch >> 2, off = ch & 3;
            f32x4 av = *(const f32x4*)&Ap[(size_t)(c0 + row) * S + k0 + off * 8];
            f32x4 bv = *(const f32x4*)&Bp[(size_t)(n0 + row) * S + k0 + off * 8];
            *(f32x4*)&As[row * 40 + off * 8] = av;
            *(f32x4*)&Bs[row * 40 + off * 8] = bv;
        }
        __syncthreads();

        s16x8 af[4], bf[4];
        #pragma unroll
        for (int f = 0; f < 4; ++f) {
            af[f] = *(const s16x8*)&As[(wr * 64 + f * 16 + r15) * 40 + q * 8];
            bf[f] = *(const s16x8*)&Bs[(wc * 64 + f * 16 + r15) * 40 + q * 8];
        }
        #pragma unroll
        for (int i = 0; i < 4; ++i)
            #pragma unroll
            for (int j = 0; j < 4; ++j)
                acc[i][j] = __builtin_amdgcn_mfma_f32_16x16x32_bf16(af[i], bf[j], acc[i][j], 0, 0, 0);
    }

    // epilogue: out = acc / L[n] + a  (L = sum of 16 per-m-tile partials)
    float rcpL[4];
    #pragma unroll
    for (int j = 0; j < 4; ++j) {
        int n = n0 + wc * 64 + j * 16 + r15;
        float s = 0.f;
        #pragma unroll
        for (int mt = 0; mt < NMT; ++mt)
            s += Lp[(size_t)lb * NMT * S + (size_t)mt * S + n];
        rcpL[j] = 1.0f / s;
    }
    #pragma unroll
    for (int i = 0; i < 4; ++i) {
        #pragma unroll
        for (int rr = 0; rr < 4; ++rr) {
            int cc = c0 + wr * 64 + i * 16 + q * 4 + rr;
            size_t base = (size_t)cc * S;
            #pragma unroll
            for (int j = 0; j < 4; ++j) {
                int n = n0 + wc * 64 + j * 16 + r15;
                op[base + n] = acc[i][j][rr] * rcpL[j] + ap[base + n];
            }
        }
    }
}

// ---------------- launch ----------------
extern "C" void kernel_launch(void* const* d_in, const int* in_sizes, int n_in,
                              void* d_out, int out_size, void* d_ws, size_t ws_size,
                              hipStream_t stream) {
    const float* a = (const float*)d_in[0];
    const float* b = (const float*)d_in[1];
    const float* c = (const float*)d_in[2];
    float* out = (float*)d_out;

    const size_t a16_bytes = (size_t)NBATCH * CDIM * S * 2;              // 8 MB
    const size_t perb = (size_t)S * S * 2 + (size_t)NMT * S * 4;         // ~8.5 MB per batch
    int G = 1;
    if (ws_size > a16_bytes + perb) {
        size_t g = (ws_size - a16_bytes) / perb;
        G = (g >= NBATCH) ? NBATCH : (int)g;
        if (G < 1) G = 1;
    }
    unsigned short* a16 = (unsigned short*)d_ws;
    unsigned short* E = (unsigned short*)((char*)d_ws + a16_bytes);
    float* Lp = (float*)((char*)d_ws + a16_bytes + (size_t)G * S * S * 2);

    cvt_a_kernel<<<1024, 256, 0, stream>>>(a, a16, NBATCH * CDIM * S / 4);

    const size_t lds1 = 2 * 128 * 72 * 2 + 2 * 128 * 4;   // 37888 B
    for (int b0 = 0; b0 < NBATCH; b0 += G) {
        int nb = (NBATCH - b0 < G) ? (NBATCH - b0) : G;
        dim3 g1(NMT, S / 128, nb);
        scores_kernel<<<g1, 256, lds1, stream>>>(b, c, E, Lp, b0);
        dim3 g2(S / 128, CDIM / 128, nb);
        gemm_kernel<<<g2, 256, 0, stream>>>(a16, E, Lp, a, out, b0);
    }
}